// Round 8
// baseline (299.112 us; speedup 1.0000x reference)
//
#include <hip/hip_runtime.h>
#include <math.h>

#define CHN 128
#define TT 16384
#define NBATCH 8
#define KCONST 196608      // 128*128*3*4
#define TILE_T 96          // stored rows per tile
#define GUARD 8
#define CRANGE 128         // computed range per layer: [T0-16, T0+112)
#define ROWS 144           // CRANGE + 2*GUARD, t = T0 - 24 + row
#define LROW 128           // ushorts per LDS row (256 B); 16B chunks XOR-swizzled
#define FRAG 512           // elems per A-frag (64 lanes x 8)
#define KSN 12             // ks steps per layer
#define OTILE_STRIDE (KSN * FRAG)      // 6144 elems per o-tile
#define BL_STRIDE (8 * OTILE_STRIDE)   // 49152 elems per (b,layer)
#define NTILES 171         // ceil(16384/96)

typedef __bf16 bf16x8 __attribute__((ext_vector_type(8)));
typedef float  f32x4  __attribute__((ext_vector_type(4)));
typedef unsigned short u16x8 __attribute__((ext_vector_type(8)));
typedef unsigned short u16x4 __attribute__((ext_vector_type(4)));

__device__ __forceinline__ unsigned short f2bf(float f) {
    union { float f; unsigned int u; } v; v.f = f;
    unsigned int u = v.u;
    u += 0x7fffu + ((u >> 16) & 1u);   // round-to-nearest-even
    return (unsigned short)(u >> 16);
}
__device__ __forceinline__ float b2f(unsigned short h) {
    union { float f; unsigned int u; } v; v.u = ((unsigned int)h) << 16;
    return v.f;
}

__device__ __forceinline__ float gelu_exact(float x) {
    return 0.5f * x * (1.0f + erff(x * 0.70710678118654752f));
}

// ------------- Kernel 1a: conv0 (80->64, k=5, pad=2) + gelu -> h0 -------------
__global__ __launch_bounds__(256) void k_cond0(
    const float* __restrict__ cond, const float* __restrict__ w0,
    const float* __restrict__ b0, float* __restrict__ h0)
{
    __shared__ float cS[80 * 32];
    __shared__ float wS[8 * 80 * 5];
    __shared__ float bS[8];
    int b = blockIdx.x >> 3, g = blockIdx.x & 7;
    int tid = threadIdx.x;

    for (int idx = tid; idx < 80 * 32; idx += 256) cS[idx] = cond[b * 2560 + idx];
    for (int idx = tid; idx < 8 * 400; idx += 256) wS[idx] = w0[g * 3200 + idx];
    if (tid < 8) bS[tid] = b0[g * 8 + tid];
    __syncthreads();

    int oc = tid >> 5, t = tid & 31;
    float acc = bS[oc];
    const float* wr = wS + oc * 400;
    for (int ic = 0; ic < 80; ++ic) {
        const float* cr = cS + ic * 32;
        #pragma unroll
        for (int j = 0; j < 5; ++j) {
            int tv = t - 2 + j;
            if (tv >= 0 && tv < 32) acc += wr[ic * 5 + j] * cr[tv];
        }
    }
    h0[(b * 64 + g * 8 + oc) * 32 + t] = gelu_exact(acc);
}

// ------ Kernel 1b: conv1 (64->64, k=3, pad=1) + gelu + mean_t -> hbar --------
__global__ __launch_bounds__(256) void k_cond1(
    const float* __restrict__ h0, const float* __restrict__ w1,
    const float* __restrict__ b1, float* __restrict__ hbar)
{
    __shared__ float hS[64 * 32];
    __shared__ float wS[8 * 64 * 3];
    __shared__ float bS[8];
    int b = blockIdx.x >> 3, g = blockIdx.x & 7;
    int tid = threadIdx.x;

    for (int idx = tid; idx < 64 * 32; idx += 256) hS[idx] = h0[b * 2048 + idx];
    for (int idx = tid; idx < 8 * 192; idx += 256) wS[idx] = w1[g * 1536 + idx];
    if (tid < 8) bS[tid] = b1[g * 8 + tid];
    __syncthreads();

    int oc = tid >> 5, t = tid & 31;
    float acc = bS[oc];
    const float* wr = wS + oc * 192;
    for (int ic = 0; ic < 64; ++ic) {
        const float* hr = hS + ic * 32;
        #pragma unroll
        for (int j = 0; j < 3; ++j) {
            int tv = t - 1 + j;
            if (tv >= 0 && tv < 32) acc += wr[ic * 3 + j] * hr[tv];
        }
    }
    float v = gelu_exact(acc);
    #pragma unroll
    for (int off = 1; off < 32; off <<= 1) v += __shfl_xor(v, off, 64);
    if (t == 0) hbar[b * 64 + g * 8 + oc] = v * (1.0f / 32.0f);
}

// ---- Kernel 2: kernels/biases. LDS-staged coalesced w2 reads. ----
// W output layout (v7, verified): frag-contiguous for the MFMA consumer:
//   W[((bl*8 + o>>4)*12 + ks)*512 + quad*128 + (o&15)*8 + (c&7)]
//   where ks = tp*4 + (c>>5), quad = (c>>3)&3.
// One wave's A-frag (16 o-rows x 32 k) is a contiguous 1024 B block with
// lane i at base + i*16 B -- ideal coalescing (round 6: 258->162 us).
__global__ __launch_bounds__(256) void k_weights(
    const float* __restrict__ w2, const float* __restrict__ b2,
    const float* __restrict__ hbar,
    unsigned short* __restrict__ W, float* __restrict__ bmean)
{
    __shared__ float hS[8 * 64];
    __shared__ float buf[256 * 68];   // 256 rows x 64 floats, +4 pad
    int tid = threadIdx.x;
    for (int idx = tid; idx < 512; idx += 256) hS[idx] = hbar[idx];

    // stage this block's 256 w2 rows (64 KB) via coalesced float4 stream
    const float4* src4 = (const float4*)(w2 + (long)blockIdx.x * 16384);
    #pragma unroll
    for (int it = 0; it < 16; ++it) {
        int f = it * 256 + tid;
        float4 v = src4[f];
        int row = f >> 4, col = f & 15;
        *(float4*)&buf[row * 68 + col * 4] = v;
    }
    __syncthreads();

    long p = (long)blockIdx.x * 256 + tid;   // [0, 197632), exact
    const float* rowp = &buf[tid * 68];
    float acc[8];
    #pragma unroll
    for (int bb = 0; bb < 8; ++bb) acc[bb] = 0.f;
    #pragma unroll
    for (int q = 0; q < 16; ++q) {
        float4 wv = *(const float4*)&rowp[q * 4];
        #pragma unroll
        for (int bb = 0; bb < 8; ++bb) {
            const float* h = hS + bb * 64 + q * 4;
            acc[bb] += wv.x * h[0] + wv.y * h[1] + wv.z * h[2] + wv.w * h[3];
        }
    }
    float bias = b2[p];
    if (p < KCONST) {
        int i = (int)(p / 49152); int r = (int)(p % 49152);
        int o = r / 384; int m = r % 384; int c = m / 3; int tp = m % 3;
        int ks = tp * 4 + (c >> 5);
        int within = ((c >> 3) & 3) * 128 + (o & 15) * 8 + (c & 7);
        long fbase = ((long)(o >> 4) * KSN + ks) * FRAG + within;
        #pragma unroll
        for (int bb = 0; bb < 8; ++bb)
            W[(long)(bb * 4 + i) * BL_STRIDE + fbase] = f2bf(acc[bb] + bias);
    } else {
        int q = (int)(p - KCONST); int i = q >> 7, o = q & 127;
        #pragma unroll
        for (int bb = 0; bb < 8; ++bb)
            bmean[(bb * 4 + i) * 128 + o] = acc[bb] + bias;
    }
}

// ------ Kernel 3: ALL 4 dilated conv layers fused, signal lives in LDS ------
// v9 = v8 with TILE_T=96 + single-buffer in-place (occupancy trade):
// - TILE_T 96: computes 128 rows to store 96 (1.33x halo) vs 64-tile's 1.5x
//   -> -11% flops, -11% staging, grid 171x8 = 1368 blocks.
// - Single 144-row buffer (36,864 B; dbuf at 73.7 KB exceeds the 64 KB static
//   LDS cap) -> 3-4 blocks/CU instead of 2. In-place update costs 2 barriers
//   per layer (7 total vs v8's 4); cross-block waves hide the drain.
// - Wave split, A-frag layout, B-read, writeback, C/D mapping: IDENTICAL to
//   v8 (verified) -- only nt count 3->4 and tb 48->64 change.
// In-place validity: guard rows keep original x (never overwritten), so each
// layer's edge outputs that consumed guards are corrupt-but-finite; valid
// range shrinks by d per side per layer: after l3 valid [T0-2, T0+98) superset
// of stored [T0, T0+96). fp32 residual chain lives in the MFMA accumulator
// (C-in carries x_l, never re-zeroed); acc initialized from x cache-hot.
// __launch_bounds__(512,4): 128-reg cap, proven no-spill regime (v8: 60 regs;
// v9 adds 8 acc regs + 1 nt of B-frags -> ~80). WRITE_SIZE > 70 MB = spill.
__global__ __launch_bounds__(512, 4) void k_fused(
    const float* __restrict__ src, float* __restrict__ dst,
    const unsigned short* __restrict__ W, const float* __restrict__ bmean,
    const float* __restrict__ alpha)
{
    __shared__ __align__(16) unsigned short xs[ROWS * LROW];  // 36864 B

    int tid  = threadIdx.x;
    int lane = tid & 63;
    int wave = tid >> 6;          // 0..7
    int b    = blockIdx.y;
    int T0   = blockIdx.x * TILE_T;

    int nrow = lane & 15;
    int quad = lane >> 4;
    int wm   = wave & 3;          // o-quarter (32 ch)
    int wn   = wave >> 2;         // t-half (64 computed rows)
    int o0   = wm * 32;
    int tb   = wn * 64;           // row offset within the 128 computed rows

    const float* xb = src + (long)b * CHN * TT;

    // --- stage x (bf16) into the swizzled LDS image ---
    // pass 0: rows 0..127 (wn*64 + lane); pass 1: rows 128..143 (wn==0,
    // lanes 0..15). Each wave covers its 32-channel slice.
    {
        int cb   = wm * 32;
        int c16b = wm * 4;        // chunk base = cb/8
        {
            int tl = wn * 64 + lane;       // 0..127 < ROWS
            int tg = T0 - 24 + tl;
            bool ok = (tg >= 0) && (tg < TT);
            int sw = tl & 7;
            #pragma unroll
            for (int kb = 0; kb < 4; ++kb) {
                float v[8];
                #pragma unroll
                for (int k = 0; k < 8; ++k)
                    v[k] = ok ? xb[(long)(cb + kb * 8 + k) * TT + tg] : 0.f;
                u16x8 h;
                #pragma unroll
                for (int k = 0; k < 8; ++k) h[k] = f2bf(v[k]);
                *(u16x8*)&xs[tl * LROW + (((c16b + kb) ^ sw) << 3)] = h;
            }
        }
        if (wn == 0 && lane < 16) {
            int tl = 128 + lane;           // 128..143
            int tg = T0 - 24 + tl;
            bool ok = (tg >= 0) && (tg < TT);
            int sw = tl & 7;
            #pragma unroll
            for (int kb = 0; kb < 4; ++kb) {
                float v[8];
                #pragma unroll
                for (int k = 0; k < 8; ++k)
                    v[k] = ok ? xb[(long)(cb + kb * 8 + k) * TT + tg] : 0.f;
                u16x8 h;
                #pragma unroll
                for (int k = 0; k < 8; ++k) h[k] = f2bf(v[k]);
                *(u16x8*)&xs[tl * LROW + (((c16b + kb) ^ sw) << 3)] = h;
            }
        }
    }

    // persistent fp32 accumulator = residual chain; init acc = x (cache-hot)
    f32x4 acc[2][4];
    #pragma unroll
    for (int m = 0; m < 2; ++m) {
        int obase = o0 + m * 16 + quad * 4;
        #pragma unroll
        for (int nt = 0; nt < 4; ++nt) {
            int tg = T0 - 16 + tb + nt * 16 + nrow;
            bool ok = ((unsigned)tg < (unsigned)TT);
            #pragma unroll
            for (int r = 0; r < 4; ++r)
                acc[m][nt][r] = ok ? xb[(long)(obase + r) * TT + tg] : 0.f;
        }
    }

    __syncthreads();

    #pragma unroll 1
    for (int l = 0; l < 4; ++l) {
        const int d = 1 << l;
        // frag-contiguous W: this wave's 2 o-tiles are (wm*2, wm*2+1)
        const unsigned short* Wl =
            W + (long)(b * 4 + l) * BL_STRIDE + (long)(wm * 2) * OTILE_STRIDE
              + lane * 8;

        // K-loop: 2 dense 1024 B A-loads per ks + 4 swizzled B ds_reads;
        // B-frag feeds 2 m-tiles; MFMA C-in carries x_l (fp32 residual)
        #pragma unroll
        for (int ks = 0; ks < 12; ++ks) {
            int roff = GUARD + tb + nrow + ((ks >> 2) - 1) * d;
            int ch   = (((ks & 3) * 4 + quad) ^ (roff & 7)) << 3;
            const unsigned short* wr = Wl + ks * FRAG;
            bf16x8 a0 = *(const bf16x8*)(wr);
            bf16x8 a1 = *(const bf16x8*)(wr + OTILE_STRIDE);
            #pragma unroll
            for (int nt = 0; nt < 4; ++nt) {
                bf16x8 bf =
                    *(const bf16x8*)&xs[(roff + nt * 16) * LROW + ch];
                acc[0][nt] = __builtin_amdgcn_mfma_f32_16x16x32_bf16(
                    a0, bf, acc[0][nt], 0, 0, 0);
                acc[1][nt] = __builtin_amdgcn_mfma_f32_16x16x32_bf16(
                    a1, bf, acc[1][nt], 0, 0, 0);
            }
        }

        // bias (small, L2-hot) folded into acc (residual already in acc)
        {
            const float* bm = bmean + (b * 4 + l) * 128;
            #pragma unroll
            for (int m = 0; m < 2; ++m) {
                int obase = o0 + m * 16 + quad * 4;
                #pragma unroll
                for (int r = 0; r < 4; ++r) {
                    float bv = bm[obase + r];
                    #pragma unroll
                    for (int nt = 0; nt < 4; ++nt)
                        acc[m][nt][r] += bv;
                }
            }
        }

        __syncthreads();   // all in-place reads of layer l done before writes

        if (l < 3) {
            // write back the bf16 image for layer l+1 IN PLACE (swizzled)
            #pragma unroll
            for (int m = 0; m < 2; ++m) {
                int obase = o0 + m * 16 + quad * 4;
                int ch0 = obase >> 3, sub = obase & 7;
                #pragma unroll
                for (int nt = 0; nt < 4; ++nt) {
                    int trow = GUARD + tb + nt * 16 + nrow;
                    int tg = T0 - 16 + tb + nt * 16 + nrow;
                    bool ok = ((unsigned)tg < (unsigned)TT);
                    u16x4 h;
                    #pragma unroll
                    for (int r = 0; r < 4; ++r) {
                        float v = ok ? acc[m][nt][r] : 0.f;
                        h[r] = f2bf(v);
                    }
                    *(u16x4*)&xs[trow * LROW +
                                 (((ch0 ^ (trow & 7)) << 3) + sub)] = h;
                }
            }
            __syncthreads();   // writeback visible -> next layer may read
        } else {
            // final layer: sin activation, store only the valid 96-t core
            #pragma unroll
            for (int m = 0; m < 2; ++m) {
                #pragma unroll
                for (int r = 0; r < 4; ++r) {
                    int o = o0 + m * 16 + quad * 4 + r;
                    float av = alpha[o];
                    float rcp = 1.0f / (av + 1e-8f);
                    long rowoff = ((long)b * CHN + o) * TT + T0;
                    #pragma unroll
                    for (int nt = 0; nt < 4; ++nt) {
                        int trel0 = tb + nt * 16 - 16;
                        if ((unsigned)trel0 < 96u) {   // wave-uniform guard
                            int tg = T0 + trel0 + nrow;
                            if (tg < TT) {             // last-tile clip
                                float xn = acc[m][nt][r];
                                float s = __sinf(av * xn);
                                dst[rowoff + trel0 + nrow] =
                                    xn + rcp * s * s;
                            }
                        }
                    }
                }
            }
        }
    }
}

extern "C" void kernel_launch(void* const* d_in, const int* in_sizes, int n_in,
                              void* d_out, int out_size, void* d_ws, size_t ws_size,
                              hipStream_t stream) {
    const float* x     = (const float*)d_in[0];
    const float* cond  = (const float*)d_in[1];
    const float* w0    = (const float*)d_in[2];
    const float* b0    = (const float*)d_in[3];
    const float* w1    = (const float*)d_in[4];
    const float* b1    = (const float*)d_in[5];
    const float* w2    = (const float*)d_in[6];
    const float* b2    = (const float*)d_in[7];
    const float* alpha = (const float*)d_in[8];
    float* out = (float*)d_out;

    char* ws = (char*)d_ws;
    unsigned short* W = (unsigned short*)ws;               // 3,145,728 B
    float* bmean = (float*)(ws + 3145728);                 // 16,384 B
    float* hbar  = (float*)(ws + 3162112);                 // 2,048 B
    float* h0    = (float*)(ws + 3164160);                 // 65,536 B

    k_cond0<<<64, 256, 0, stream>>>(cond, w0, b0, h0);
    k_cond1<<<64, 256, 0, stream>>>(h0, w1, b1, hbar);
    k_weights<<<772, 256, 0, stream>>>(w2, b2, hbar, W, bmean);
    k_fused<<<dim3(NTILES, NBATCH), 512, 0, stream>>>(x, out, W, bmean, alpha);
}